// Round 5
// baseline (264.938 us; speedup 1.0000x reference)
//
#include <hip/hip_runtime.h>
#include <math.h>

constexpr int S_LEN = 4096;
constexpr int W     = 32;            // steps per window
constexpr int NP    = W / 2;         // 16 step-pairs per window
constexpr int NW    = S_LEN / W;     // 128 windows
constexpr int CPB   = 32;            // chains per block

// lane 2k <-> 2k+1 swap via DPP quad_perm [1,0,3,2]
__device__ __forceinline__ float pair_swap(float v) {
    int j = __builtin_amdgcn_mov_dpp(__builtin_bit_cast(int, v), 0xB1, 0xF, 0xF, true);
    return __builtin_bit_cast(float, j);
}

// Quaternion reformulation (verified R3):
//   u_{t+1} = N(u_t + b_t),  b_t = L e_t R^{-(t+1)};  measurement invariant under R^S.
// Deferred norm: g unnormalized, rn = 1/|g|;  one step: g' = rn g + b, rn' = rsqrt(2+2 rn <g,b>).
// PAIR-FUSED (2 steps, shortens serial chain to rn->fma->rsqrt->fma->rsqrt):
//   d0=<g,b0>, d1=<g,b1> (parallel);  c01=<b0,b1> (producer-precomputed)
//   m0 = 2+2 rn d0 ; rn0 = rsqrt(m0)
//   e1 = rn d1 + c01 ; m1 = 2+2 rn0 e1 ; rn1 = rsqrt(m1)
//   g'' = rn0 (rn g + b0) + b1 ; rn <- rn1
// Layout (all float4, no type-punning):
//   bbuf4[sel][pair][2c+p] = (b0[2p], b0[2p+1], b1[2p], b1[2p+1])  -> ds_read_b128 @16B*lane
//   c01buf[sel][pair][c]   = <b0,b1>                                -> broadcast read
__global__ __launch_bounds__(192)
void qrnn_kernel(const float* __restrict__ x,
                 const float* __restrict__ alpha_p,
                 const float* __restrict__ beta_p,
                 float* __restrict__ out)
{
    __shared__ float4 bbuf4[2 * NP * 2 * CPB];   // 32 KB
    __shared__ float  c01buf[2 * NP * CPB];      //  4 KB
    __shared__ float2 wtab[NW];                  //  1 KB  cs(w*32*hb)
    __shared__ float2 stab[W];                   // 256 B  cs((s+1)*hb)

    const int tid = threadIdx.x;

    // ---- two-level (C,S) tables, f64 angle reduction (as in R3) ----
    {
        const double hb     = 0.5 * (double)beta_p[0];
        const double twopi  = 6.283185307179586476925287;
        const double inv2pi = 0.15915494309189533576888;
        for (int t = tid; t < NW + W; t += 192) {
            double ang = (t < NW) ? (double)(t * W) * hb : (double)(t - NW + 1) * hb;
            ang -= floor(ang * inv2pi) * twopi;
            float sv, cv;
            __sincosf((float)ang, &sv, &cv);
            if (t < NW) wtab[t] = make_float2(cv, sv);
            else        stab[t - NW] = make_float2(cv, sv);
        }
    }
    __syncthreads();

    if (tid >= 64) {
        // ================= PRODUCERS (waves 1,2) — R3 pattern =================
        float sa, ca;
        __sincosf(0.5f * alpha_p[0], &sa, &ca);

        const int plane = tid - 64;          // 0..127
        const int c     = plane & 31;        // chain within block
        const int half  = plane >> 5;        // 0..3 -> 8 steps (4 pairs) each
        const float4* __restrict__ xrow =
            reinterpret_cast<const float4*>(x) +
            (size_t)(blockIdx.x * CPB + c) * (S_LEN / 4);

        auto fill = [&](int w, const float4& cA, const float4& cB) {
            const int sel = w & 1;
            const float2 wt = wtab[w];
            float xv[8] = {cA.x, cA.y, cA.z, cA.w, cB.x, cB.y, cB.z, cB.w};
#pragma unroll
            for (int jj = 0; jj < 4; ++jj) {
                float b0[4], b1[4];
#pragma unroll
                for (int ii = 0; ii < 2; ++ii) {
                    const int i = jj * 2 + ii;
                    const int s = half * 8 + i;
                    float2 st = stab[s];
                    float C = __builtin_fmaf(wt.x, st.x, -(wt.y * st.y));
                    float S = __builtin_fmaf(wt.y, st.x,  (wt.x * st.y));
                    float xt  = xv[i];
                    float t1  = __builtin_fmaf(xt, xt, 1.0f);
                    float r   = __frsqrt_rn(t1);                 // cos(phi)
                    float wvv = __builtin_fmaf(0.5f, r, 0.5f);   // c^2
                    float v   = __frsqrt_rn(wvv);
                    float cc  = wvv * v;                         // c
                    float xr  = xt * r;                          // sin(phi)
                    float ssv = xr * (0.5f * v);                 // s
                    float e1 = cc * C,  e2 = cc * S;
                    float e3 = ssv * C, e4 = ssv * S;
                    float* b = ii ? b1 : b0;
                    b[0] =  __builtin_fmaf(ca, e1, -(sa * e4));
                    b[1] = -__builtin_fmaf(ca, e2,  (sa * e3));
                    b[2] =  __builtin_fmaf(ca, e3, -(sa * e2));
                    b[3] =  __builtin_fmaf(sa, e1,  (ca * e4));
                }
                float c01 = b0[0] * b1[0];
                c01 = __builtin_fmaf(b0[1], b1[1], c01);
                c01 = __builtin_fmaf(b0[2], b1[2], c01);
                c01 = __builtin_fmaf(b0[3], b1[3], c01);
                const int pair = half * 4 + jj;
                const int base = (sel * NP + pair) * 64 + 2 * c;
                bbuf4[base]     = make_float4(b0[0], b0[1], b1[0], b1[1]);
                bbuf4[base + 1] = make_float4(b0[2], b0[3], b1[2], b1[3]);
                c01buf[(sel * NP + pair) * CPB + c] = c01;
            }
        };

        // window 0, then prefetch window 1 (R3 skeleton)
        float4 a0 = xrow[half * 2];
        float4 a1 = xrow[half * 2 + 1];
        fill(0, a0, a1);
        float4 n0 = xrow[8 + half * 2];
        float4 n1 = xrow[8 + half * 2 + 1];
        __syncthreads();                      // window 0 ready

        for (int w = 0; w < NW; ++w) {
            if (w + 1 < NW) {
                float4 b0 = n0, b1 = n1;
                if (w + 2 < NW) {
                    n0 = xrow[(w + 2) * 8 + half * 2];
                    n1 = xrow[(w + 2) * 8 + half * 2 + 1];
                }
                fill(w + 1, b0, b1);
            }
            __syncthreads();
        }
    } else {
        // ================= CONSUMER (wave 0) =================
        const int lane = tid;                 // 0..63 = 2c+p
        const int p    = lane & 1;
        const int chn  = lane >> 1;

        float gx = 0.f, gy = 0.f, rn = 1.f;

        __syncthreads();                      // wait window 0

        for (int w = 0; w < NW; ++w) {
            const int sel = w & 1;
            const float4* __restrict__ bb = &bbuf4[sel * NP * 64 + lane];
            const float*  __restrict__ cp = &c01buf[sel * NP * CPB + chn];

            auto pairstep = [&](int j) {
                float4 v   = bb[j * 64];
                float c01v = cp[j * CPB];
                float d0p = __builtin_fmaf(gy, v.y, gx * v.x);
                float d1p = __builtin_fmaf(gy, v.w, gx * v.z);
                float d0  = d0p + pair_swap(d0p);
                float d1  = d1p + pair_swap(d1p);
                float d0x2 = d0 + d0;
                float m0   = __builtin_fmaf(rn, d0x2, 2.0f);
                float rn0  = __frsqrt_rn(m0);
                float e1   = __builtin_fmaf(rn, d1, c01v);
                float e1x2 = e1 + e1;
                float m1   = __builtin_fmaf(rn0, e1x2, 2.0f);
                float ngx  = __builtin_fmaf(rn, gx, v.x);
                float ngy  = __builtin_fmaf(rn, gy, v.y);
                gx = __builtin_fmaf(rn0, ngx, v.z);
                gy = __builtin_fmaf(rn0, ngy, v.w);
                rn = __frsqrt_rn(m1);
            };

            if (w == 0) {
                // pair 0 peeled exactly: u2 = N(b0 + b1), |b0|=|b1|=1
                float4 v   = bb[0];
                float c01v = cp[0];
                gx = v.x + v.z;
                gy = v.y + v.w;
                rn = __frsqrt_rn(__builtin_fmaf(c01v, 2.0f, 2.0f));
#pragma unroll
                for (int j = 1; j < NP; ++j) pairstep(j);
            } else {
#pragma unroll
                for (int j = 0; j < NP; ++j) pairstep(j);
            }
            __syncthreads();
        }

        float ss = __builtin_fmaf(gy, gy, gx * gx);
        float so = pair_swap(ss);
        if (p == 0) out[blockIdx.x * CPB + chn] = (ss - so) / (ss + so);
    }
}

extern "C" void kernel_launch(void* const* d_in, const int* in_sizes, int n_in,
                              void* d_out, int out_size, void* d_ws, size_t ws_size,
                              hipStream_t stream) {
    const float* x       = (const float*)d_in[0];
    const float* alpha_p = (const float*)d_in[1];
    const float* beta_p  = (const float*)d_in[2];
    float* out = (float*)d_out;
    int grid = out_size / CPB;               // 8192/32 = 256 blocks
    qrnn_kernel<<<grid, 192, 0, stream>>>(x, alpha_p, beta_p, out);
}